// Round 5
// baseline (994.221 us; speedup 1.0000x reference)
//
#include <hip/hip_runtime.h>
#include <math.h>

#define B_N 256
#define T_N 1024
#define D_N 128
#define H_N 256

// LDS row strides in bf16 units. Rule: stride in 16B units must be ODD for
// conflict-free ds_read_b128 (136->17, 120->15).
#define SXS 136
#define SPS 120

// LDS map (shorts): sX | sP | sQ | guard(8) | accum(256 f32)
#define SX_OFF   0
#define SP_OFF   8704          // 64*136
#define SQ_OFF   16384         // +64*120
#define GUARD    24064         // +64*120  (16B zeroed: keeps K-overrun reads finite)
#define ACC_OFF  24072         // floats from here (256 floats = 512 shorts)
#define SMEM_SH  24584

typedef __attribute__((ext_vector_type(8))) short short8;   // 8 bf16 = 4 VGPRs
typedef __attribute__((ext_vector_type(4))) float f32x4;

// ws layout (bf16 units): transposed zero-padded weights WT[Npad][Kpad]
#define WXT_OFF 0         // [256][128]
#define W1T_OFF 32768     // [112][128]
#define W2T_OFF 47104     // [112][128]  rows k>=100 are ZERO (lets A be garbage there)
#define W3T_OFF 61440     // [112][128]
#define W4T_OFF 75776     // [ 64][128]
#define W5T_OFF 83968     // [256][ 64]  rows k>=50 zero
#define WT_TOTAL 100352

__device__ __forceinline__ float sigmoid_f(float z) {
    return 1.0f / (1.0f + __expf(-z));
}
__device__ __forceinline__ unsigned short f2bf(float f) {   // RNE fp32->bf16
    unsigned u = __float_as_uint(f);
    return (unsigned short)((u + 0x7FFFu + ((u >> 16) & 1u)) >> 16);
}

// ---- weight prep: fp32 W[K][N] -> bf16 WT[Npad][Kpad] (transposed, zero-padded)
__global__ __launch_bounds__(256) void prep_weights(
    const float* __restrict__ Wx, const float* __restrict__ W1,
    const float* __restrict__ W2, const float* __restrict__ W3,
    const float* __restrict__ W4, const float* __restrict__ W5,
    short* __restrict__ wt)
{
    int idx = blockIdx.x * 256 + threadIdx.x;
    if (idx >= WT_TOTAL) return;
    const float* src; int Kp, K, N, local;
    if (idx < W1T_OFF)      { src = Wx; Kp = 128; K = 128; N = 256; local = idx - WXT_OFF; }
    else if (idx < W2T_OFF) { src = W1; Kp = 128; K = 128; N = 100; local = idx - W1T_OFF; }
    else if (idx < W3T_OFF) { src = W2; Kp = 128; K = 100; N = 100; local = idx - W2T_OFF; }
    else if (idx < W4T_OFF) { src = W3; Kp = 128; K = 100; N = 100; local = idx - W3T_OFF; }
    else if (idx < W5T_OFF) { src = W4; Kp = 128; K = 100; N =  50; local = idx - W4T_OFF; }
    else                    { src = W5; Kp =  64; K =  50; N = 256; local = idx - W5T_OFF; }
    int n = local / Kp, k = local % Kp;
    float v = (k < K && n < N) ? src[(size_t)k * N + n] : 0.0f;
    wt[idx] = (short)f2bf(v);
}

// A-fragment: lane holds A[m=lane&15][k = k0 + (lane>>4)*8 + j], j=0..7
template<int STRIDE>
__device__ __forceinline__ short8 ldsA(const short* base, int mbase, int lr, int lq, int k0) {
    return *reinterpret_cast<const short8*>(&base[(mbase + lr) * STRIDE + k0 + lq * 8]);
}
// B-fragment: lane holds B[k = k0 + (lane>>4)*8 + j][n = n0 + (lane&15)] from WT[n][k]
__device__ __forceinline__ short8 ldB(const short* wt, int Kp, int n0, int lr, int lq, int k0) {
    return *reinterpret_cast<const short8*>(&wt[(size_t)(n0 + lr) * Kp + k0 + lq * 8]);
}

// Dense layer: NT N-tiles, KS K-32 steps, relu, bf16 store (cols >= ncap -> 0).
// C/D layout: row = lq*4 + r, col = n0 + lr (verified m89/m91).
// NOTE: no dynamic indexing of private arrays anywhere (R4's scratch-spill bug).
template<int NT, int KS, int INS, int OUTS>
__device__ __forceinline__ void denseL(const short* __restrict__ wt, int Kp,
                                       const float* __restrict__ bias, int ncap,
                                       const short* __restrict__ src, short* __restrict__ dst,
                                       int mbase, int lr, int lq)
{
    short8 a[KS];
    #pragma unroll
    for (int k = 0; k < KS; ++k) a[k] = ldsA<INS>(src, mbase, lr, lq, k * 32);
    const int n = lr;  // + n0 below
    #pragma unroll
    for (int nt = 0; nt < NT; ++nt) {
        const int n0 = nt * 16;
        f32x4 acc = {0.f, 0.f, 0.f, 0.f};
        #pragma unroll
        for (int k = 0; k < KS; ++k)
            acc = __builtin_amdgcn_mfma_f32_16x16x32_bf16(a[k], ldB(wt, Kp, n0, lr, lq, k * 32), acc, 0, 0, 0);
        const bool valid = (n0 + n < ncap);
        const float bv = valid ? bias[n0 + n] : 0.0f;
        #pragma unroll
        for (int r = 0; r < 4; ++r) {
            float v = valid ? fmaxf(acc[r] + bv, 0.0f) : 0.0f;
            dst[(mbase + lq * 4 + r) * OUTS + n0 + n] = (short)f2bf(v);
        }
    }
}

// Fused MLP + linearized scan (relu is identity in the scan: gate>0, hidden0=0):
//   hidden[b,h] = sum_t gate[t,b,(h - s*(T-1-t)) mod H]  =>  gate[t][j] -> h=(j+s*(T-1-t)) mod H
// 1024 blocks = 4 t-segments x 256 batch. 4 waves/block; wave w owns rows [16w,16w+16)
// of every LDS buffer for the whole chain -> no barriers in the main loop.
// x stays live in sX all round; L1..L4 ping-pong sP/sQ; tail loop fuses Lx+L5+gate+scatter.
__global__ __launch_bounds__(256, 3) void srnn_gate_scan(
    const float* __restrict__ x, const short* __restrict__ wt,
    const float* __restrict__ bx, const float* __restrict__ b1,
    const float* __restrict__ b2, const float* __restrict__ b3,
    const float* __restrict__ b4, const float* __restrict__ b5,
    const int* __restrict__ shiftp,
    float* __restrict__ out)   // out[0..255]=output, out[256..]=hidden (pre-zeroed)
{
    __shared__ __align__(16) short smem[SMEM_SH];
    short* sX = smem + SX_OFF;
    short* sP = smem + SP_OFF;
    short* sQ = smem + SQ_OFF;
    float* accum = reinterpret_cast<float*>(smem + ACC_OFF);

    const int tid = threadIdx.x;
    const int b   = blockIdx.x & 255;
    const int seg = blockIdx.x >> 8;
    const int lane = tid & 63;
    const int mbase = (tid >> 6) * 16;
    const int lr = lane & 15;         // A/B n-index; C/D col
    const int lq = lane >> 4;         // quad; C/D row = lq*4+r
    const int s = *shiftp;

    const short* WxT = wt + WXT_OFF;
    const short* W1T = wt + W1T_OFF;
    const short* W2T = wt + W2T_OFF;
    const short* W3T = wt + W3T_OFF;
    const short* W4T = wt + W4T_OFF;
    const short* W5T = wt + W5T_OFF;

    // zero sP, sQ, guard, accum (one pass; guarantees all K-overrun reads see
    // finite bf16 forever after — activations are finite, zeros are finite)
    {
        const float4 z = {0.f, 0.f, 0.f, 0.f};
        float4* dst = reinterpret_cast<float4*>(smem + SP_OFF);
        #pragma unroll
        for (int i = 0; i < 8; ++i) {
            int sl = tid + i * 256;
            if (sl < 1985) dst[sl] = z;   // (SMEM_SH - SP_OFF)/8 = 1985 float4s
        }
    }
    __syncthreads();

    for (int rd = 0; rd < 4; ++rd) {
        const int tw0 = seg * 256 + rd * 64 + mbase;   // t of this wave's row 0

        // ---- stage 16 x-rows -> sX bf16 (cols 0..127), wave-local ----
        {
            const float* xsrc = x + ((size_t)b * T_N + tw0) * D_N;
            #pragma unroll
            for (int it = 0; it < 8; ++it) {
                const int row = (lane >> 5) + it * 2;      // 0..15
                const int col = (lane & 31) * 4;
                float4 v = *reinterpret_cast<const float4*>(&xsrc[row * D_N + col]);
                uint2 p;
                p.x = (unsigned)f2bf(v.x) | ((unsigned)f2bf(v.y) << 16);
                p.y = (unsigned)f2bf(v.z) | ((unsigned)f2bf(v.w) << 16);
                *reinterpret_cast<uint2*>(&sX[(mbase + row) * SXS + col]) = p;
            }
        }

        // ---- dense chain, wave-local ping-pong; K rounded to 128 (B rows
        //      k>=real-K are exact zeros, so A overrun/garbage is harmless) ----
        denseL<7, 4, SXS, SPS>(W1T, 128, b1, 100, sX, sP, mbase, lr, lq);  // L1
        denseL<7, 4, SPS, SPS>(W2T, 128, b2, 100, sP, sQ, mbase, lr, lq);  // L2
        denseL<7, 4, SPS, SPS>(W3T, 128, b3, 100, sQ, sP, mbase, lr, lq);  // L3
        denseL<4, 4, SPS, SPS>(W4T, 128, b4,  50, sP, sQ, mbase, lr, lq);  // L4

        // ---- fused tail: Lx (128->256 from sX) + L5 (50->256 from sQ) + gate + scatter ----
        {
            short8 a0 = ldsA<SXS>(sX, mbase, lr, lq, 0),  a1 = ldsA<SXS>(sX, mbase, lr, lq, 32);
            short8 a2 = ldsA<SXS>(sX, mbase, lr, lq, 64), a3 = ldsA<SXS>(sX, mbase, lr, lq, 96);
            short8 c0 = ldsA<SPS>(sQ, mbase, lr, lq, 0),  c1 = ldsA<SPS>(sQ, mbase, lr, lq, 32);
            #pragma unroll 4
            for (int nt = 0; nt < 16; ++nt) {
                const int n0 = nt * 16;
                f32x4 ax = {0.f, 0.f, 0.f, 0.f};
                ax = __builtin_amdgcn_mfma_f32_16x16x32_bf16(a0, ldB(WxT, 128, n0, lr, lq, 0),  ax, 0, 0, 0);
                ax = __builtin_amdgcn_mfma_f32_16x16x32_bf16(a1, ldB(WxT, 128, n0, lr, lq, 32), ax, 0, 0, 0);
                ax = __builtin_amdgcn_mfma_f32_16x16x32_bf16(a2, ldB(WxT, 128, n0, lr, lq, 64), ax, 0, 0, 0);
                ax = __builtin_amdgcn_mfma_f32_16x16x32_bf16(a3, ldB(WxT, 128, n0, lr, lq, 96), ax, 0, 0, 0);
                f32x4 a5 = {0.f, 0.f, 0.f, 0.f};
                a5 = __builtin_amdgcn_mfma_f32_16x16x32_bf16(c0, ldB(W5T, 64, n0, lr, lq, 0),  a5, 0, 0, 0);
                a5 = __builtin_amdgcn_mfma_f32_16x16x32_bf16(c1, ldB(W5T, 64, n0, lr, lq, 32), a5, 0, 0, 0);
                const float bxv = bx[n0 + lr];
                const float b5v = b5[n0 + lr];
                #pragma unroll
                for (int r = 0; r < 4; ++r) {
                    const int t = tw0 + lq * 4 + r;
                    const float g = sigmoid_f(a5[r] + b5v) * sigmoid_f(ax[r] + bxv);
                    int v = n0 + lr + s * (T_N - 1 - t);
                    v %= H_N; if (v < 0) v += H_N;
                    atomicAdd(&accum[v], g);   // per-t the h-map is a bijection
                }
            }
        }
    }

    __syncthreads();
    // flush partial hidden (4 segment-blocks per b -> global atomic, out zeroed)
    atomicAdd(&out[256 + b * 256 + tid], accum[tid]);
}

// output[b] = sigmoid(hidden[b,:] @ Wo + bo)
__global__ __launch_bounds__(256) void srnn_output(
    const float* __restrict__ Wo, const float* __restrict__ bo,
    float* __restrict__ out)
{
    __shared__ float red[256];
    const int b = blockIdx.x, tid = threadIdx.x;
    red[tid] = out[256 + b * 256 + tid] * Wo[tid];
    __syncthreads();
    #pragma unroll
    for (int off = 128; off > 0; off >>= 1) {
        if (tid < off) red[tid] += red[tid + off];
        __syncthreads();
    }
    if (tid == 0) out[b] = sigmoid_f(red[0] + bo[0]);
}

extern "C" void kernel_launch(void* const* d_in, const int* in_sizes, int n_in,
                              void* d_out, int out_size, void* d_ws, size_t ws_size,
                              hipStream_t stream)
{
    const float* x  = (const float*)d_in[0];
    const float* Wx = (const float*)d_in[1];
    const float* bx = (const float*)d_in[2];
    const float* W1 = (const float*)d_in[3];
    const float* b1 = (const float*)d_in[4];
    const float* W2 = (const float*)d_in[5];
    const float* b2 = (const float*)d_in[6];
    const float* W3 = (const float*)d_in[7];
    const float* b3 = (const float*)d_in[8];
    const float* W4 = (const float*)d_in[9];
    const float* b4 = (const float*)d_in[10];
    const float* W5 = (const float*)d_in[11];
    const float* b5 = (const float*)d_in[12];
    const float* Wo = (const float*)d_in[13];
    const float* bo = (const float*)d_in[14];
    const int* shiftp = (const int*)d_in[15];
    float* out = (float*)d_out;
    short* wt  = (short*)d_ws;   // 200,704 B scratch: bf16 transposed weights

    // hidden accumulated with atomics -> zero-init (d_out is poisoned)
    hipMemsetAsync(d_out, 0, (size_t)out_size * sizeof(float), stream);

    prep_weights<<<dim3((WT_TOTAL + 255) / 256), dim3(256), 0, stream>>>(
        Wx, W1, W2, W3, W4, W5, wt);
    srnn_gate_scan<<<dim3(1024), dim3(256), 0, stream>>>(
        x, wt, bx, b1, b2, b3, b4, b5, shiftp, out);
    srnn_output<<<dim3(256), dim3(256), 0, stream>>>(Wo, bo, out);
}

// Round 6
// 651.227 us; speedup vs baseline: 1.5267x; 1.5267x over previous
//
#include <hip/hip_runtime.h>
#include <math.h>

#define B_N 256
#define T_N 1024
#define D_N 128
#define H_N 256

// LDS strides in bf16 units; 16B-unit strides are ODD -> conflict-free b128.
#define SXS 136   // x rows (17)
#define SPS 120   // activations (15)
#define SWS 136   // staged weights, Kp=128 (17)
#define SW5 72    // staged W5, Kp=64 (9)

// LDS map (shorts). sWX region is x first, then per-layer staged weights.
#define SWX_OFF 0          // 15232 shorts (sX uses 64*136=8704 of it)
#define SP_OFF  15232      // 64*120 = 7680
#define SQ_OFF  22912      // 7680
#define GUARD   30592      // 8 (zeroed; catches last-row K-overrun reads)
#define ACC_OFF 30600      // 512 shorts = 256 floats
#define SMEM_SH 31112      // 62,224 B -> 2 blocks/CU

typedef __attribute__((ext_vector_type(8))) short short8;   // 8 bf16 = 4 VGPRs
typedef __attribute__((ext_vector_type(4))) float f32x4;

// ws layout (bf16 units): transposed zero-padded weights WT[Npad][Kpad]
#define WXT_OFF 0         // [256][128]
#define W1T_OFF 32768     // [112][128]
#define W2T_OFF 47104     // [112][128]  rows k>=100 are ZERO
#define W3T_OFF 61440     // [112][128]
#define W4T_OFF 75776     // [ 64][128]
#define W5T_OFF 83968     // [256][ 64]  rows k>=50 zero
#define WT_TOTAL 100352

__device__ __forceinline__ float sigmoid_f(float z) {
    return 1.0f / (1.0f + __expf(-z));
}
__device__ __forceinline__ unsigned short f2bf(float f) {   // RNE fp32->bf16
    unsigned u = __float_as_uint(f);
    return (unsigned short)((u + 0x7FFFu + ((u >> 16) & 1u)) >> 16);
}

// ---- weight prep: fp32 W[K][N] -> bf16 WT[Npad][Kpad] (transposed, zero-padded)
__global__ __launch_bounds__(256) void prep_weights(
    const float* __restrict__ Wx, const float* __restrict__ W1,
    const float* __restrict__ W2, const float* __restrict__ W3,
    const float* __restrict__ W4, const float* __restrict__ W5,
    short* __restrict__ wt)
{
    int idx = blockIdx.x * 256 + threadIdx.x;
    if (idx >= WT_TOTAL) return;
    const float* src; int Kp, K, N, local;
    if (idx < W1T_OFF)      { src = Wx; Kp = 128; K = 128; N = 256; local = idx - WXT_OFF; }
    else if (idx < W2T_OFF) { src = W1; Kp = 128; K = 128; N = 100; local = idx - W1T_OFF; }
    else if (idx < W3T_OFF) { src = W2; Kp = 128; K = 100; N = 100; local = idx - W2T_OFF; }
    else if (idx < W4T_OFF) { src = W3; Kp = 128; K = 100; N = 100; local = idx - W3T_OFF; }
    else if (idx < W5T_OFF) { src = W4; Kp = 128; K = 100; N =  50; local = idx - W4T_OFF; }
    else                    { src = W5; Kp =  64; K =  50; N = 256; local = idx - W5T_OFF; }
    int n = local / Kp, k = local % Kp;
    float v = (k < K && n < N) ? src[(size_t)k * N + n] : 0.0f;
    wt[idx] = (short)f2bf(v);
}

// Cooperative global->LDS weight stage: NR rows of KP shorts -> stride STR.
// All row/slot counts are exact multiples of 256 threads.
template<int NR, int KP, int STR>
__device__ __forceinline__ void coop_load(const short* __restrict__ g,
                                          short* __restrict__ dst, int tid)
{
    constexpr int SPR = KP / 8;        // b128 slots per row (16 or 8)
    constexpr int TOT = NR * SPR;
    #pragma unroll
    for (int i = 0; i < TOT / 256; ++i) {
        const int sl = tid + i * 256;
        const int r  = sl / SPR;
        const int c  = sl & (SPR - 1);
        *reinterpret_cast<short8*>(dst + r * STR + c * 8) =
            *reinterpret_cast<const short8*>(g + (size_t)r * KP + c * 8);
    }
}

// A-fragment set (K=128): lane holds A[m=lr][k = k*32 + lq*8 + j]
template<int STRIDE>
__device__ __forceinline__ void loadA(const short* __restrict__ base, short8 (&a)[4],
                                      int mbase, int lr, int lq)
{
    #pragma unroll
    for (int k = 0; k < 4; ++k)
        a[k] = *reinterpret_cast<const short8*>(&base[(mbase + lr) * STRIDE + k * 32 + lq * 8]);
}

// Dense layer: A in regs, B from staged LDS (stride SWS), relu, bf16 store.
// C/D layout: row = lq*4+r, col = n0+lr (verified m89/m91).
template<int NT, int OUTS>
__device__ __forceinline__ void denseL(const short8 (&a)[4], const short* __restrict__ sW,
                                       const float* __restrict__ bias, int ncap,
                                       short* __restrict__ dst, int mbase, int lr, int lq)
{
    #pragma unroll 2
    for (int nt = 0; nt < NT; ++nt) {
        const int n0 = nt * 16;
        f32x4 acc = {0.f, 0.f, 0.f, 0.f};
        #pragma unroll
        for (int k = 0; k < 4; ++k) {
            const short8 bf = *reinterpret_cast<const short8*>(&sW[(n0 + lr) * SWS + k * 32 + lq * 8]);
            acc = __builtin_amdgcn_mfma_f32_16x16x32_bf16(a[k], bf, acc, 0, 0, 0);
        }
        const bool valid = (n0 + lr < ncap);
        const float bv = valid ? bias[n0 + lr] : 0.0f;
        #pragma unroll
        for (int r = 0; r < 4; ++r) {
            float v = valid ? fmaxf(acc[r] + bv, 0.0f) : 0.0f;
            dst[(mbase + lq * 4 + r) * OUTS + n0 + lr] = (short)f2bf(v);
        }
    }
}

// Fused MLP + linearized scan (relu is identity in scan: gate>0, hidden0=0):
//   hidden[b,h] = sum_t gate[t,b,(h - s*(T-1-t)) mod H] => gate[t][j] -> h=(j+s*(T-1-t)) mod H
// Grid 4096 = 16 t-segments x 256 batch; block = 4 waves x 16 t-rows.
// Weights staged per-layer into shared LDS (sWX region); A and B both ds_read_b128.
__global__ __launch_bounds__(256, 2) void srnn_gate_scan(
    const float* __restrict__ x, const short* __restrict__ wt,
    const float* __restrict__ bx, const float* __restrict__ b1,
    const float* __restrict__ b2, const float* __restrict__ b3,
    const float* __restrict__ b4, const float* __restrict__ b5,
    const int* __restrict__ shiftp,
    float* __restrict__ out)   // out[0..255]=output, out[256..]=hidden (pre-zeroed)
{
    __shared__ __align__(16) short smem[SMEM_SH];
    short* sWX = smem + SWX_OFF;    // x, then staged weights
    short* sP  = smem + SP_OFF;
    short* sQ  = smem + SQ_OFF;
    float* accum = reinterpret_cast<float*>(smem + ACC_OFF);

    const int tid  = threadIdx.x;
    const int b    = blockIdx.x & 255;
    const int seg  = blockIdx.x >> 8;      // 0..15
    const int lane = tid & 63;
    const int mbase = (tid >> 6) * 16;     // wave's row base in LDS
    const int lr = lane & 15;              // A m-index / B n-index / C-D col
    const int lq = lane >> 4;              // quad; C/D row = lq*4+r
    const int s  = *shiftp;
    const int tw0 = seg * 64 + mbase;      // t of this wave's row 0

    // zero sP..end (activations pads, guard, accum) -> all K-overrun reads finite
    {
        const float4 z = {0.f, 0.f, 0.f, 0.f};
        float4* dst = reinterpret_cast<float4*>(smem + SP_OFF);
        #pragma unroll
        for (int i = 0; i < 8; ++i) {
            int sl = tid + i * 256;
            if (sl < (SMEM_SH - SP_OFF) / 8) dst[sl] = z;
        }
    }

    // ---- stage this wave's 16 x-rows -> sX bf16 (wave-local, in-order) ----
    {
        const float* xsrc = x + ((size_t)b * T_N + tw0) * D_N;
        #pragma unroll
        for (int it = 0; it < 8; ++it) {
            const int row = (lane >> 5) + it * 2;      // 0..15
            const int col = (lane & 31) * 4;
            float4 v = *reinterpret_cast<const float4*>(&xsrc[row * D_N + col]);
            uint2 p;
            p.x = (unsigned)f2bf(v.x) | ((unsigned)f2bf(v.y) << 16);
            p.y = (unsigned)f2bf(v.z) | ((unsigned)f2bf(v.w) << 16);
            *reinterpret_cast<uint2*>(&sWX[(mbase + row) * SXS + col]) = p;
        }
    }
    // grab x A-fragments NOW (serve both L1 and the tail's Lx); sX dies after
    short8 ax4[4];
    loadA<SXS>(sWX, ax4, mbase, lr, lq);
    __syncthreads();                       // everyone done with sX

    short8 aL[4];
    // ---- L1 ----
    coop_load<112, 128, SWS>(wt + W1T_OFF, sWX, tid);
    __syncthreads();
    denseL<7, SPS>(ax4, sWX, b1, 100, sP, mbase, lr, lq);
    __syncthreads();
    // ---- L2 ----
    coop_load<112, 128, SWS>(wt + W2T_OFF, sWX, tid);
    loadA<SPS>(sP, aL, mbase, lr, lq);     // wave-local read of own L1 output
    __syncthreads();
    denseL<7, SPS>(aL, sWX, b2, 100, sQ, mbase, lr, lq);
    __syncthreads();
    // ---- L3 ----
    coop_load<112, 128, SWS>(wt + W3T_OFF, sWX, tid);
    loadA<SPS>(sQ, aL, mbase, lr, lq);
    __syncthreads();
    denseL<7, SPS>(aL, sWX, b3, 100, sP, mbase, lr, lq);
    __syncthreads();
    // ---- L4 ----
    coop_load<64, 128, SWS>(wt + W4T_OFF, sWX, tid);
    loadA<SPS>(sP, aL, mbase, lr, lq);
    __syncthreads();
    denseL<4, SPS>(aL, sWX, b4, 50, sQ, mbase, lr, lq);
    __syncthreads();

    // ---- tail: Lx (A=ax4) + L5 (A from sQ, K=64) + gate + scatter, 4 n-chunks ----
    short8 c0, c1;
    c0 = *reinterpret_cast<const short8*>(&sQ[(mbase + lr) * SPS + 0 + lq * 8]);
    c1 = *reinterpret_cast<const short8*>(&sQ[(mbase + lr) * SPS + 32 + lq * 8]);
    short* sW5s = sWX + 8704;
    for (int ch = 0; ch < 4; ++ch) {
        coop_load<64, 128, SWS>(wt + WXT_OFF + ch * 64 * 128, sWX, tid);
        coop_load<64, 64, SW5>(wt + W5T_OFF + ch * 64 * 64, sW5s, tid);
        __syncthreads();
        #pragma unroll 2
        for (int ntl = 0; ntl < 4; ++ntl) {
            const int n0  = ntl * 16;
            const int gn0 = ch * 64 + n0;
            f32x4 axv = {0.f, 0.f, 0.f, 0.f};
            #pragma unroll
            for (int k = 0; k < 4; ++k) {
                const short8 bf = *reinterpret_cast<const short8*>(&sWX[(n0 + lr) * SWS + k * 32 + lq * 8]);
                axv = __builtin_amdgcn_mfma_f32_16x16x32_bf16(ax4[k], bf, axv, 0, 0, 0);
            }
            f32x4 a5v = {0.f, 0.f, 0.f, 0.f};
            {
                const short8 bf0 = *reinterpret_cast<const short8*>(&sW5s[(n0 + lr) * SW5 + 0 + lq * 8]);
                const short8 bf1 = *reinterpret_cast<const short8*>(&sW5s[(n0 + lr) * SW5 + 32 + lq * 8]);
                a5v = __builtin_amdgcn_mfma_f32_16x16x32_bf16(c0, bf0, a5v, 0, 0, 0);
                a5v = __builtin_amdgcn_mfma_f32_16x16x32_bf16(c1, bf1, a5v, 0, 0, 0);
            }
            const float bxv = bx[gn0 + lr];
            const float b5v = b5[gn0 + lr];
            #pragma unroll
            for (int r = 0; r < 4; ++r) {
                const int t = tw0 + lq * 4 + r;
                const float g = sigmoid_f(a5v[r] + b5v) * sigmoid_f(axv[r] + bxv);
                int v = gn0 + lr + s * (T_N - 1 - t);
                v %= H_N; if (v < 0) v += H_N;
                atomicAdd(&accum[v], g);   // per-t the h-map is a bijection
            }
        }
        __syncthreads();
    }

    // flush partial hidden (16 segment-blocks per b -> global atomic, out zeroed)
    atomicAdd(&out[256 + b * 256 + tid], accum[tid]);
}

// output[b] = sigmoid(hidden[b,:] @ Wo + bo)
__global__ __launch_bounds__(256) void srnn_output(
    const float* __restrict__ Wo, const float* __restrict__ bo,
    float* __restrict__ out)
{
    __shared__ float red[256];
    const int b = blockIdx.x, tid = threadIdx.x;
    red[tid] = out[256 + b * 256 + tid] * Wo[tid];
    __syncthreads();
    #pragma unroll
    for (int off = 128; off > 0; off >>= 1) {
        if (tid < off) red[tid] += red[tid + off];
        __syncthreads();
    }
    if (tid == 0) out[b] = sigmoid_f(red[0] + bo[0]);
}

extern "C" void kernel_launch(void* const* d_in, const int* in_sizes, int n_in,
                              void* d_out, int out_size, void* d_ws, size_t ws_size,
                              hipStream_t stream)
{
    const float* x  = (const float*)d_in[0];
    const float* Wx = (const float*)d_in[1];
    const float* bx = (const float*)d_in[2];
    const float* W1 = (const float*)d_in[3];
    const float* b1 = (const float*)d_in[4];
    const float* W2 = (const float*)d_in[5];
    const float* b2 = (const float*)d_in[6];
    const float* W3 = (const float*)d_in[7];
    const float* b3 = (const float*)d_in[8];
    const float* W4 = (const float*)d_in[9];
    const float* b4 = (const float*)d_in[10];
    const float* W5 = (const float*)d_in[11];
    const float* b5 = (const float*)d_in[12];
    const float* Wo = (const float*)d_in[13];
    const float* bo = (const float*)d_in[14];
    const int* shiftp = (const int*)d_in[15];
    float* out = (float*)d_out;
    short* wt  = (short*)d_ws;   // 200,704 B scratch: bf16 transposed weights

    // hidden accumulated with atomics -> zero-init (d_out is poisoned)
    hipMemsetAsync(d_out, 0, (size_t)out_size * sizeof(float), stream);

    prep_weights<<<dim3((WT_TOTAL + 255) / 256), dim3(256), 0, stream>>>(
        Wx, W1, W2, W3, W4, W5, wt);
    srnn_gate_scan<<<dim3(4096), dim3(256), 0, stream>>>(
        x, wt, bx, b1, b2, b3, b4, b5, shiftp, out);
    srnn_output<<<dim3(256), dim3(256), 0, stream>>>(Wo, bo, out);
}